// Round 7
// baseline (81.775 us; speedup 1.0000x reference)
//
#include <hip/hip_runtime.h>
#include <math.h>

typedef __attribute__((ext_vector_type(8))) short short8;
typedef __attribute__((ext_vector_type(4))) float f32x4;

constexpr int D    = 64;
constexpr int BT_N = 64;     // block tile rows (x)
constexpr int BT_M = 512;    // block tile cols (y), 8 subtiles of 64
constexpr int NSUB = 8;

__device__ inline float fastcos_rev(float r) {
#if __has_builtin(__builtin_amdgcn_cosf)
    return __builtin_amdgcn_cosf(r);
#else
    return __cosf(r * 6.283185307179586f);
#endif
}
__device__ inline float fastsin_rev(float r) {
#if __has_builtin(__builtin_amdgcn_sinf)
    return __builtin_amdgcn_sinf(r);
#else
    return __sinf(r * 6.283185307179586f);
#endif
}

// split f into bf16 hi + bf16 lo via truncation: f = hi + r exactly, lo = trunc_bf16(r)
__device__ inline void split8(const float* v, short8& hi, short8& lo) {
    #pragma unroll
    for (int j = 0; j < 8; ++j) {
        unsigned u = __builtin_bit_cast(unsigned, v[j]);
        hi[j] = (short)(u >> 16);
        float hf = __builtin_bit_cast(float, u & 0xffff0000u);
        float r  = v[j] - hf;
        lo[j] = (short)(__builtin_bit_cast(unsigned, r) >> 16);
    }
}

// ---------------- prep: 8 threads/row; scale+split+pack + row stats ----------------
// packed tile layout (per 16 rows): ushort idx = (kslice*16 + row%16)*8 + e
// -> a wave's fragment read (lane = lg*16+l15) is lane*16 bytes: fully coalesced.
__global__ __launch_bounds__(256) void prep_kernel(
    const float* __restrict__ x, const float* __restrict__ y,
    const float* __restrict__ mu, const float* __restrict__ ls2,
    unsigned short* __restrict__ xh, unsigned short* __restrict__ xl,
    unsigned short* __restrict__ yh, unsigned short* __restrict__ yl,
    float4* __restrict__ xst, float4* __restrict__ yst,
    int BN, int BM)
{
    __shared__ float ss[D], sm[D];
    const int t = threadIdx.x;
    if (t < D) { ss[t] = __expf(0.5f * ls2[t]); sm[t] = mu[t]; }
    __syncthreads();

    const int gid = blockIdx.x * 256 + t;
    const int row = gid >> 3;         // one row per 8 consecutive lanes
    const int sub = gid & 7;          // k-slice 8*sub .. 8*sub+7
    if (row >= BN + BM) return;

    const float* src;
    unsigned short *ph, *pl;
    float4* pst;
    int r;
    if (row < BN) { r = row;      src = x + (size_t)r * D; ph = xh; pl = xl; pst = xst; }
    else          { r = row - BN; src = y + (size_t)r * D; ph = yh; pl = yl; pst = yst; }

    const int k0 = sub * 8;
    float4 u0 = *(const float4*)(src + k0);
    float4 u1 = *(const float4*)(src + k0 + 4);
    const float4 m0 = *(const float4*)&sm[k0];
    const float4 m1 = *(const float4*)&sm[k0 + 4];
    const float4 s0 = *(const float4*)&ss[k0];
    const float4 s1 = *(const float4*)&ss[k0 + 4];

    float m = u0.x*m0.x + u0.y*m0.y + u0.z*m0.z + u0.w*m0.w
            + u1.x*m1.x + u1.y*m1.y + u1.z*m1.z + u1.w*m1.w;
    u0.x *= s0.x; u0.y *= s0.y; u0.z *= s0.z; u0.w *= s0.w;
    u1.x *= s1.x; u1.y *= s1.y; u1.z *= s1.z; u1.w *= s1.w;
    float h = u0.x*u0.x + u0.y*u0.y + u0.z*u0.z + u0.w*u0.w
            + u1.x*u1.x + u1.y*u1.y + u1.z*u1.z + u1.w*u1.w;

    // reduce m,h across the 8 lanes of this row
    m += __shfl_xor(m, 1); m += __shfl_xor(m, 2); m += __shfl_xor(m, 4);
    h += __shfl_xor(h, 1); h += __shfl_xor(h, 2); h += __shfl_xor(h, 4);

    if (sub == 0) {
        constexpr float INV2PI = 0.15915494309189535f;
        float rr = m * INV2PI;
        rr -= floorf(rr);
        pst[r] = (float4){0.5f * h, fastcos_rev(rr), fastsin_rev(rr), 0.f};
    }

    float v[8] = {u0.x, u0.y, u0.z, u0.w, u1.x, u1.y, u1.z, u1.w};
    short8 hi, lo;
    split8(v, hi, lo);
    const size_t o = (size_t)(r >> 4) * 1024 + (size_t)(sub * 16 + (r & 15)) * 8;
    *(short8*)(ph + o) = hi;
    *(short8*)(pl + o) = lo;
}

// ---------------- main: 64x512 tile, 4 waves (2x2), loop over 8 m-subtiles ----------------
// Single-buffered loads; full unroll + __restrict__ lets the compiler hoist the
// next subtile's loads above the current stores within the 128-VGPR budget.
// Stats are read from LDS in the epilogue (not hoisted) to stay under the cliff.
__global__ __launch_bounds__(256, 4) void main_kernel(
    const unsigned short* __restrict__ xh, const unsigned short* __restrict__ xl,
    const unsigned short* __restrict__ yh, const unsigned short* __restrict__ yl,
    const float4* __restrict__ xst, const float4* __restrict__ yst,
    float* __restrict__ out, int N, int M)
{
    __shared__ float4 stA[BT_N], stB[BT_M];

    const int b  = blockIdx.z;
    const int n0 = blockIdx.y * BT_N;
    const int m0 = blockIdx.x * BT_M;
    const int t  = threadIdx.x;

    stB[t]       = yst[(size_t)b * M + m0 + t];
    stB[t + 256] = yst[(size_t)b * M + m0 + 256 + t];
    if (t < BT_N) stA[t] = xst[(size_t)b * N + n0 + t];
    __syncthreads();

    const int w = t >> 6, lane = t & 63;
    const int wr = w >> 1, wc = w & 1;
    const int l15 = lane & 15, lg = lane >> 4;

    // packed-tile base pointers (ushort units)
    const size_t tA0 = (((size_t)b * N + n0) >> 4) + wr * 2;
    const size_t tB0 = (((size_t)b * M + m0) >> 4) + wc * 2;
    const unsigned short* xbh = xh + tA0 * 1024 + (size_t)lane * 8;
    const unsigned short* xbl = xl + tA0 * 1024 + (size_t)lane * 8;
    const unsigned short* ybh = yh + tB0 * 1024 + (size_t)lane * 8;
    const unsigned short* ybl = yl + tB0 * 1024 + (size_t)lane * 8;

    // A fragments: load once, hold for all 8 subtiles (32 VGPR)
    short8 ah[2][2], al[2][2];
    #pragma unroll
    for (int kc = 0; kc < 2; ++kc)
        #pragma unroll
        for (int i = 0; i < 2; ++i) {
            ah[kc][i] = *(const short8*)(xbh + i * 1024 + kc * 512);
            al[kc][i] = *(const short8*)(xbl + i * 1024 + kc * 512);
        }

    float* outb = out + ((size_t)b * N + n0 + wr * 32 + lg * 4) * (size_t)M
                + m0 + wc * 32 + l15;

    #pragma unroll
    for (int st = 0; st < NSUB; ++st) {
        // B fragments for this subtile (32 VGPR, single-buffered)
        short8 bh[2][2], bl[2][2];
        #pragma unroll
        for (int kc = 0; kc < 2; ++kc)
            #pragma unroll
            for (int j = 0; j < 2; ++j) {
                const size_t o = (size_t)st * 4096 + j * 1024 + kc * 512;
                bh[kc][j] = *(const short8*)(ybh + o);
                bl[kc][j] = *(const short8*)(ybl + o);
            }

        f32x4 acc[2][2];
        #pragma unroll
        for (int i = 0; i < 2; ++i)
            #pragma unroll
            for (int j = 0; j < 2; ++j)
                acc[i][j] = (f32x4){0.f, 0.f, 0.f, 0.f};

        #pragma unroll
        for (int kc = 0; kc < 2; ++kc)
            #pragma unroll
            for (int i = 0; i < 2; ++i)
                #pragma unroll
                for (int j = 0; j < 2; ++j) {
                    acc[i][j] = __builtin_amdgcn_mfma_f32_16x16x32_bf16(ah[kc][i], bh[kc][j], acc[i][j], 0, 0, 0);
                    acc[i][j] = __builtin_amdgcn_mfma_f32_16x16x32_bf16(ah[kc][i], bl[kc][j], acc[i][j], 0, 0, 0);
                    acc[i][j] = __builtin_amdgcn_mfma_f32_16x16x32_bf16(al[kc][i], bh[kc][j], acc[i][j], 0, 0, 0);
                }

        // epilogue: out = (cx*cy + sx*sy) * exp(xy - hx - hy)
        const float4 sb0 = stB[st * 64 + wc * 32 + l15];        // C/D col = l15 -> m
        const float4 sb1 = stB[st * 64 + wc * 32 + 16 + l15];
        #pragma unroll
        for (int i = 0; i < 2; ++i)
            #pragma unroll
            for (int q = 0; q < 4; ++q) {                       // C/D row = lg*4+q -> n
                const float4 sa = stA[wr * 32 + i * 16 + lg * 4 + q];
                {
                    const float e  = (acc[i][0][q] - sa.x) - sb0.x;
                    const float cv = sa.y * sb0.y + sa.z * sb0.z;
                    outb[(size_t)(i * 16 + q) * M + st * 64] = cv * __expf(e);
                }
                {
                    const float e  = (acc[i][1][q] - sa.x) - sb1.x;
                    const float cv = sa.y * sb1.y + sa.z * sb1.z;
                    outb[(size_t)(i * 16 + q) * M + st * 64 + 16] = cv * __expf(e);
                }
            }
    }
}

// ---------------- fallback (round-1 kernel, used if shapes/ws don't fit) ----------------
constexpr int FTILE = 64;
constexpr int FPAD  = 68;
__global__ __launch_bounds__(256) void fallback_kernel(
    const float* __restrict__ x, const float* __restrict__ y,
    const float* __restrict__ mu, const float* __restrict__ ls2,
    float* __restrict__ out, int N, int M)
{
    __shared__ float xs[FTILE][FPAD];
    __shared__ float ys[FTILE][FPAD];
    __shared__ float musc[D];
    __shared__ float sx2[FTILE], smx[FTILE], sy2[FTILE], smy[FTILE];

    const int b  = blockIdx.z;
    const int n0 = blockIdx.y * FTILE;
    const int m0 = blockIdx.x * FTILE;
    const int t  = threadIdx.x;
    const int cc = t & 15, rr = t >> 4, c4 = cc * 4;

    const float s0 = __expf(0.5f * ls2[c4+0]);
    const float s1 = __expf(0.5f * ls2[c4+1]);
    const float s2 = __expf(0.5f * ls2[c4+2]);
    const float s3 = __expf(0.5f * ls2[c4+3]);
    const float* xb = x + ((size_t)b * N + n0) * D;
    const float* yb = y + ((size_t)b * M + m0) * D;

    #pragma unroll
    for (int r = 0; r < 4; ++r) {
        const int row = rr * 4 + r;
        const float4 vx = *(const float4*)(xb + row * D + c4);
        const float4 vy = *(const float4*)(yb + row * D + c4);
        xs[row][c4+0] = vx.x * s0; xs[row][c4+1] = vx.y * s1;
        xs[row][c4+2] = vx.z * s2; xs[row][c4+3] = vx.w * s3;
        ys[row][c4+0] = vy.x * s0; ys[row][c4+1] = vy.y * s1;
        ys[row][c4+2] = vy.z * s2; ys[row][c4+3] = vy.w * s3;
    }
    if (t < D) musc[t] = mu[t] * __expf(-0.5f * ls2[t]);
    __syncthreads();

    if (t < 64) {
        float a2 = 0.f, am = 0.f;
        #pragma unroll
        for (int d4 = 0; d4 < D; d4 += 4) {
            const float4 v = *(const float4*)&xs[t][d4];
            const float4 m4 = *(const float4*)&musc[d4];
            a2 += v.x*v.x + v.y*v.y + v.z*v.z + v.w*v.w;
            am += v.x*m4.x + v.y*m4.y + v.z*m4.z + v.w*m4.w;
        }
        sx2[t] = a2; smx[t] = am;
    } else if (t < 128) {
        const int r2 = t - 64;
        float a2 = 0.f, am = 0.f;
        #pragma unroll
        for (int d4 = 0; d4 < D; d4 += 4) {
            const float4 v = *(const float4*)&ys[r2][d4];
            const float4 m4 = *(const float4*)&musc[d4];
            a2 += v.x*v.x + v.y*v.y + v.z*v.z + v.w*v.w;
            am += v.x*m4.x + v.y*m4.y + v.z*m4.z + v.w*m4.w;
        }
        sy2[r2] = a2; smy[r2] = am;
    }
    __syncthreads();

    const int tx = t & 15, ty = t >> 4;
    float acc[4][4] = {};
    #pragma unroll
    for (int d = 0; d < D; d += 4) {
        float4 a4[4], b4[4];
        #pragma unroll
        for (int i = 0; i < 4; ++i) a4[i] = *(const float4*)&xs[ty + 16*i][d];
        #pragma unroll
        for (int j = 0; j < 4; ++j) b4[j] = *(const float4*)&ys[tx + 16*j][d];
        #pragma unroll
        for (int i = 0; i < 4; ++i)
            #pragma unroll
            for (int j = 0; j < 4; ++j) {
                acc[i][j] += a4[i].x*b4[j].x + a4[i].y*b4[j].y
                           + a4[i].z*b4[j].z + a4[i].w*b4[j].w;
            }
    }

    constexpr float INV2PI = 0.15915494309189535f;
    #pragma unroll
    for (int i = 0; i < 4; ++i) {
        const int nl = ty + 16*i;
        float* orow = out + ((size_t)(b * N + n0 + nl)) * (size_t)M + m0;
        const float x2v = sx2[nl], mxv = smx[nl];
        #pragma unroll
        for (int j = 0; j < 4; ++j) {
            const int ml = tx + 16*j;
            float sqd = fmaxf(x2v + sy2[ml] - 2.0f*acc[i][j], 0.0f);
            float r = (mxv - smy[ml]) * INV2PI;
            r -= floorf(r);
            orow[ml] = fastcos_rev(r) * __expf(-0.5f * sqd);
        }
    }
}

extern "C" void kernel_launch(void* const* d_in, const int* in_sizes, int n_in,
                              void* d_out, int out_size, void* d_ws, size_t ws_size,
                              hipStream_t stream)
{
    const float* x   = (const float*)d_in[0];
    const float* y   = (const float*)d_in[1];
    const float* mu  = (const float*)d_in[2];
    const float* ls2 = (const float*)d_in[3];
    float* out = (float*)d_out;

    const int Dd = in_sizes[3];
    const long long BN = in_sizes[0] / Dd;   // B*N
    const long long BM = in_sizes[1] / Dd;   // B*M
    const int B = (int)((BN * BM) / (long long)out_size);
    const int N = (int)(BN / B);
    const int M = (int)(BM / B);

    const size_t need = (size_t)(BN + BM) * D * 2 * 2   // hi+lo bf16
                      + (size_t)(BN + BM) * sizeof(float4);

    if (ws_size >= need && (N % BT_N) == 0 && (M % BT_M) == 0) {
        unsigned short* xh = (unsigned short*)d_ws;
        unsigned short* xl = xh + (size_t)BN * D;
        unsigned short* yh = xl + (size_t)BN * D;
        unsigned short* yl = yh + (size_t)BM * D;
        float4* xst = (float4*)(yl + (size_t)BM * D);
        float4* yst = xst + BN;

        const long long rows8 = (BN + BM) * 8;
        hipLaunchKernelGGL(prep_kernel, dim3((int)((rows8 + 255) / 256)), dim3(256), 0, stream,
                           x, y, mu, ls2, xh, xl, yh, yl, xst, yst, (int)BN, (int)BM);
        hipLaunchKernelGGL(main_kernel, dim3(M / BT_M, N / BT_N, B), dim3(256), 0, stream,
                           xh, xl, yh, yl, xst, yst, out, N, M);
    } else {
        hipLaunchKernelGGL(fallback_kernel, dim3(M / FTILE, N / FTILE, B), dim3(256), 0, stream,
                           x, y, mu, ls2, out, N, M);
    }
}

// Round 8
// 65.044 us; speedup vs baseline: 1.2572x; 1.2572x over previous
//
#include <hip/hip_runtime.h>
#include <math.h>

typedef __attribute__((ext_vector_type(8))) short short8;
typedef __attribute__((ext_vector_type(4))) float f32x4;

constexpr int D    = 64;
constexpr int BT_N = 64;     // block tile rows (x)
constexpr int BT_M = 512;    // block tile cols (y), 8 subtiles of 64
constexpr int NSUB = 8;

__device__ inline float fastcos_rev(float r) {
#if __has_builtin(__builtin_amdgcn_cosf)
    return __builtin_amdgcn_cosf(r);
#else
    return __cosf(r * 6.283185307179586f);
#endif
}
__device__ inline float fastsin_rev(float r) {
#if __has_builtin(__builtin_amdgcn_sinf)
    return __builtin_amdgcn_sinf(r);
#else
    return __sinf(r * 6.283185307179586f);
#endif
}

// split f into bf16 hi + bf16 lo via truncation: f = hi + r exactly, lo = trunc_bf16(r)
__device__ inline void split8(const float* v, short8& hi, short8& lo) {
    #pragma unroll
    for (int j = 0; j < 8; ++j) {
        unsigned u = __builtin_bit_cast(unsigned, v[j]);
        hi[j] = (short)(u >> 16);
        float hf = __builtin_bit_cast(float, u & 0xffff0000u);
        float r  = v[j] - hf;
        lo[j] = (short)(__builtin_bit_cast(unsigned, r) >> 16);
    }
}

// split one float to bf16 hi/lo
__device__ inline void split1(float f, short& hi, short& lo) {
    unsigned u = __builtin_bit_cast(unsigned, f);
    hi = (short)(u >> 16);
    float hf = __builtin_bit_cast(float, u & 0xffff0000u);
    lo = (short)(__builtin_bit_cast(unsigned, f - hf) >> 16);
}

// ---------------- prep: 8 threads/row; scale+split+pack + row stats ----------------
// packed tile layout (per 16 rows): ushort idx = (kslice*16 + row%16)*8 + e
// -> a wave's fragment read (lane = lg*16+l15) is lane*16 bytes: fully coalesced.
__global__ __launch_bounds__(256) void prep_kernel(
    const float* __restrict__ x, const float* __restrict__ y,
    const float* __restrict__ mu, const float* __restrict__ ls2,
    unsigned short* __restrict__ xh, unsigned short* __restrict__ xl,
    unsigned short* __restrict__ yh, unsigned short* __restrict__ yl,
    float4* __restrict__ xst, float4* __restrict__ yst,
    int BN, int BM)
{
    __shared__ float ss[D], sm[D];
    const int t = threadIdx.x;
    if (t < D) { ss[t] = __expf(0.5f * ls2[t]); sm[t] = mu[t]; }
    __syncthreads();

    const int gid = blockIdx.x * 256 + t;
    const int row = gid >> 3;         // one row per 8 consecutive lanes
    const int sub = gid & 7;          // k-slice 8*sub .. 8*sub+7
    if (row >= BN + BM) return;

    const float* src;
    unsigned short *ph, *pl;
    float4* pst;
    int r;
    if (row < BN) { r = row;      src = x + (size_t)r * D; ph = xh; pl = xl; pst = xst; }
    else          { r = row - BN; src = y + (size_t)r * D; ph = yh; pl = yl; pst = yst; }

    const int k0 = sub * 8;
    float4 u0 = *(const float4*)(src + k0);
    float4 u1 = *(const float4*)(src + k0 + 4);
    const float4 m0 = *(const float4*)&sm[k0];
    const float4 m1 = *(const float4*)&sm[k0 + 4];
    const float4 s0 = *(const float4*)&ss[k0];
    const float4 s1 = *(const float4*)&ss[k0 + 4];

    float m = u0.x*m0.x + u0.y*m0.y + u0.z*m0.z + u0.w*m0.w
            + u1.x*m1.x + u1.y*m1.y + u1.z*m1.z + u1.w*m1.w;
    u0.x *= s0.x; u0.y *= s0.y; u0.z *= s0.z; u0.w *= s0.w;
    u1.x *= s1.x; u1.y *= s1.y; u1.z *= s1.z; u1.w *= s1.w;
    float h = u0.x*u0.x + u0.y*u0.y + u0.z*u0.z + u0.w*u0.w
            + u1.x*u1.x + u1.y*u1.y + u1.z*u1.z + u1.w*u1.w;

    // reduce m,h across the 8 lanes of this row
    m += __shfl_xor(m, 1); m += __shfl_xor(m, 2); m += __shfl_xor(m, 4);
    h += __shfl_xor(h, 1); h += __shfl_xor(h, 2); h += __shfl_xor(h, 4);

    if (sub == 0) {
        constexpr float INV2PI = 0.15915494309189535f;
        float rr = m * INV2PI;
        rr -= floorf(rr);
        pst[r] = (float4){0.5f * h, fastcos_rev(rr), fastsin_rev(rr), 0.f};
    }

    float v[8] = {u0.x, u0.y, u0.z, u0.w, u1.x, u1.y, u1.z, u1.w};
    short8 hi, lo;
    split8(v, hi, lo);
    const size_t o = (size_t)(r >> 4) * 1024 + (size_t)(sub * 16 + (r & 15)) * 8;
    *(short8*)(ph + o) = hi;
    *(short8*)(pl + o) = lo;
}

// ---------------- main helpers ----------------
__device__ __forceinline__ void load_b(
    short8 (&bh)[2][2], short8 (&bl)[2][2],
    const unsigned short* __restrict__ ybh, const unsigned short* __restrict__ ybl,
    int st)
{
    #pragma unroll
    for (int kc = 0; kc < 2; ++kc)
        #pragma unroll
        for (int j = 0; j < 2; ++j) {
            const size_t o = (size_t)st * 4096 + j * 1024 + kc * 512;
            bh[kc][j] = *(const short8*)(ybh + o);
            bl[kc][j] = *(const short8*)(ybl + o);
        }
}

__device__ __forceinline__ void compute_store(
    const short8 (&ah)[2][2], const short8 (&al)[2][2],
    const short8 (&exA)[2],
    const short8 (&bh)[2][2], const short8 (&bl)[2][2],
    const float4* __restrict__ stB,
    const float (&say)[2][4], const float (&saz)[2][4],
    float* __restrict__ outb, int M, int st, int wc, int l15, int lg)
{
    // extra B fragment per j: k-pad [1, 1, -hy_hi, -hy_lo] (lanes lg==0 only)
    short8 exB[2];
    #pragma unroll
    for (int j = 0; j < 2; ++j) {
        const float hy = -stB[st * 64 + wc * 32 + j * 16 + l15].x;
        short hh, hl;
        split1(hy, hh, hl);
        short8 v = (short8){0,0,0,0,0,0,0,0};
        if (lg == 0) { v[0] = (short)0x3f80; v[1] = (short)0x3f80; v[2] = hh; v[3] = hl; }
        exB[j] = v;
    }

    f32x4 acc[2][2];
    #pragma unroll
    for (int i = 0; i < 2; ++i)
        #pragma unroll
        for (int j = 0; j < 2; ++j)
            acc[i][j] = (f32x4){0.f, 0.f, 0.f, 0.f};

    #pragma unroll
    for (int kc = 0; kc < 2; ++kc)
        #pragma unroll
        for (int i = 0; i < 2; ++i)
            #pragma unroll
            for (int j = 0; j < 2; ++j) {
                acc[i][j] = __builtin_amdgcn_mfma_f32_16x16x32_bf16(ah[kc][i], bh[kc][j], acc[i][j], 0, 0, 0);
                acc[i][j] = __builtin_amdgcn_mfma_f32_16x16x32_bf16(ah[kc][i], bl[kc][j], acc[i][j], 0, 0, 0);
                acc[i][j] = __builtin_amdgcn_mfma_f32_16x16x32_bf16(al[kc][i], bh[kc][j], acc[i][j], 0, 0, 0);
            }
    // fold -hx - hy into the accumulator (matrix pipe, not VALU)
    #pragma unroll
    for (int i = 0; i < 2; ++i)
        #pragma unroll
        for (int j = 0; j < 2; ++j)
            acc[i][j] = __builtin_amdgcn_mfma_f32_16x16x32_bf16(exA[i], exB[j], acc[i][j], 0, 0, 0);

    // epilogue: out = (cx*cy + sx*sy) * exp(acc)   (acc already = xy - hx - hy)
    const float4 sb0 = stB[st * 64 + wc * 32 + l15];        // C/D col = l15 -> m
    const float4 sb1 = stB[st * 64 + wc * 32 + 16 + l15];
    #pragma unroll
    for (int i = 0; i < 2; ++i)
        #pragma unroll
        for (int q = 0; q < 4; ++q) {                       // C/D row = lg*4+q -> n
            {
                const float cv = say[i][q] * sb0.y + saz[i][q] * sb0.z;
                outb[(size_t)(i * 16 + q) * M + st * 64] = cv * __expf(acc[i][0][q]);
            }
            {
                const float cv = say[i][q] * sb1.y + saz[i][q] * sb1.z;
                outb[(size_t)(i * 16 + q) * M + st * 64 + 16] = cv * __expf(acc[i][1][q]);
            }
        }
}

// ---------------- main: 64x512 tile, 4 waves (2x2), pipelined over 8 m-subtiles ----------------
__global__ __launch_bounds__(256) void main_kernel(
    const unsigned short* __restrict__ xh, const unsigned short* __restrict__ xl,
    const unsigned short* __restrict__ yh, const unsigned short* __restrict__ yl,
    const float4* __restrict__ xst, const float4* __restrict__ yst,
    float* __restrict__ out, int N, int M)
{
    __shared__ float4 stA[BT_N], stB[BT_M];

    const int b  = blockIdx.z;
    const int n0 = blockIdx.y * BT_N;
    const int m0 = blockIdx.x * BT_M;
    const int t  = threadIdx.x;

    stB[t]       = yst[(size_t)b * M + m0 + t];
    stB[t + 256] = yst[(size_t)b * M + m0 + 256 + t];
    if (t < BT_N) stA[t] = xst[(size_t)b * N + n0 + t];
    __syncthreads();

    const int w = t >> 6, lane = t & 63;
    const int wr = w >> 1, wc = w & 1;
    const int l15 = lane & 15, lg = lane >> 4;

    // packed-tile base pointers (ushort units)
    const size_t tA0 = (((size_t)b * N + n0) >> 4) + wr * 2;
    const size_t tB0 = (((size_t)b * M + m0) >> 4) + wc * 2;
    const unsigned short* xbh = xh + tA0 * 1024 + (size_t)lane * 8;
    const unsigned short* xbl = xl + tA0 * 1024 + (size_t)lane * 8;
    const unsigned short* ybh = yh + tB0 * 1024 + (size_t)lane * 8;
    const unsigned short* ybl = yl + tB0 * 1024 + (size_t)lane * 8;

    // A fragments: load once, hold for all 8 subtiles (32 VGPR)
    short8 ah[2][2], al[2][2];
    #pragma unroll
    for (int kc = 0; kc < 2; ++kc)
        #pragma unroll
        for (int i = 0; i < 2; ++i) {
            ah[kc][i] = *(const short8*)(xbh + i * 1024 + kc * 512);
            al[kc][i] = *(const short8*)(xbl + i * 1024 + kc * 512);
        }

    // extra A fragment per i: k-pad [-hx_hi, -hx_lo, 1, 1] (lanes lg==0 only)
    short8 exA[2];
    #pragma unroll
    for (int i = 0; i < 2; ++i) {
        const float hx = -stA[wr * 32 + i * 16 + l15].x;
        short hh, hl;
        split1(hx, hh, hl);
        short8 v = (short8){0,0,0,0,0,0,0,0};
        if (lg == 0) { v[0] = hh; v[1] = hl; v[2] = (short)0x3f80; v[3] = (short)0x3f80; }
        exA[i] = v;
    }

    // per-n cos/sin stats hoisted (rows indexed by lg*4+q)
    float say[2][4], saz[2][4];
    #pragma unroll
    for (int i = 0; i < 2; ++i)
        #pragma unroll
        for (int q = 0; q < 4; ++q) {
            const float4 v = stA[wr * 32 + i * 16 + lg * 4 + q];
            say[i][q] = v.y; saz[i][q] = v.z;
        }

    float* outb = out + ((size_t)b * N + n0 + wr * 32 + lg * 4) * (size_t)M
                + m0 + wc * 32 + l15;

    // software pipeline: prefetch B(st+1) before compute/store of B(st)
    short8 bh0[2][2], bl0[2][2], bh1[2][2], bl1[2][2];
    load_b(bh0, bl0, ybh, ybl, 0);
    #pragma unroll
    for (int st = 0; st < NSUB; st += 2) {
        if (st + 1 < NSUB) load_b(bh1, bl1, ybh, ybl, st + 1);
        compute_store(ah, al, exA, bh0, bl0, stB, say, saz, outb, M, st, wc, l15, lg);
        if (st + 2 < NSUB) load_b(bh0, bl0, ybh, ybl, st + 2);
        if (st + 1 < NSUB)
            compute_store(ah, al, exA, bh1, bl1, stB, say, saz, outb, M, st + 1, wc, l15, lg);
    }
}

// ---------------- fallback (round-1 kernel, used if shapes/ws don't fit) ----------------
constexpr int FTILE = 64;
constexpr int FPAD  = 68;
__global__ __launch_bounds__(256) void fallback_kernel(
    const float* __restrict__ x, const float* __restrict__ y,
    const float* __restrict__ mu, const float* __restrict__ ls2,
    float* __restrict__ out, int N, int M)
{
    __shared__ float xs[FTILE][FPAD];
    __shared__ float ys[FTILE][FPAD];
    __shared__ float musc[D];
    __shared__ float sx2[FTILE], smx[FTILE], sy2[FTILE], smy[FTILE];

    const int b  = blockIdx.z;
    const int n0 = blockIdx.y * FTILE;
    const int m0 = blockIdx.x * FTILE;
    const int t  = threadIdx.x;
    const int cc = t & 15, rr = t >> 4, c4 = cc * 4;

    const float s0 = __expf(0.5f * ls2[c4+0]);
    const float s1 = __expf(0.5f * ls2[c4+1]);
    const float s2 = __expf(0.5f * ls2[c4+2]);
    const float s3 = __expf(0.5f * ls2[c4+3]);
    const float* xb = x + ((size_t)b * N + n0) * D;
    const float* yb = y + ((size_t)b * M + m0) * D;

    #pragma unroll
    for (int r = 0; r < 4; ++r) {
        const int row = rr * 4 + r;
        const float4 vx = *(const float4*)(xb + row * D + c4);
        const float4 vy = *(const float4*)(yb + row * D + c4);
        xs[row][c4+0] = vx.x * s0; xs[row][c4+1] = vx.y * s1;
        xs[row][c4+2] = vx.z * s2; xs[row][c4+3] = vx.w * s3;
        ys[row][c4+0] = vy.x * s0; ys[row][c4+1] = vy.y * s1;
        ys[row][c4+2] = vy.z * s2; ys[row][c4+3] = vy.w * s3;
    }
    if (t < D) musc[t] = mu[t] * __expf(-0.5f * ls2[t]);
    __syncthreads();

    if (t < 64) {
        float a2 = 0.f, am = 0.f;
        #pragma unroll
        for (int d4 = 0; d4 < D; d4 += 4) {
            const float4 v = *(const float4*)&xs[t][d4];
            const float4 m4 = *(const float4*)&musc[d4];
            a2 += v.x*v.x + v.y*v.y + v.z*v.z + v.w*v.w;
            am += v.x*m4.x + v.y*m4.y + v.z*m4.z + v.w*m4.w;
        }
        sx2[t] = a2; smx[t] = am;
    } else if (t < 128) {
        const int r2 = t - 64;
        float a2 = 0.f, am = 0.f;
        #pragma unroll
        for (int d4 = 0; d4 < D; d4 += 4) {
            const float4 v = *(const float4*)&ys[r2][d4];
            const float4 m4 = *(const float4*)&musc[d4];
            a2 += v.x*v.x + v.y*v.y + v.z*v.z + v.w*v.w;
            am += v.x*m4.x + v.y*m4.y + v.z*m4.z + v.w*m4.w;
        }
        sy2[r2] = a2; smy[r2] = am;
    }
    __syncthreads();

    const int tx = t & 15, ty = t >> 4;
    float acc[4][4] = {};
    #pragma unroll
    for (int d = 0; d < D; d += 4) {
        float4 a4[4], b4[4];
        #pragma unroll
        for (int i = 0; i < 4; ++i) a4[i] = *(const float4*)&xs[ty + 16*i][d];
        #pragma unroll
        for (int j = 0; j < 4; ++j) b4[j] = *(const float4*)&ys[tx + 16*j][d];
        #pragma unroll
        for (int i = 0; i < 4; ++i)
            #pragma unroll
            for (int j = 0; j < 4; ++j) {
                acc[i][j] += a4[i].x*b4[j].x + a4[i].y*b4[j].y
                           + a4[i].z*b4[j].z + a4[i].w*b4[j].w;
            }
    }

    constexpr float INV2PI = 0.15915494309189535f;
    #pragma unroll
    for (int i = 0; i < 4; ++i) {
        const int nl = ty + 16*i;
        float* orow = out + ((size_t)(b * N + n0 + nl)) * (size_t)M + m0;
        const float x2v = sx2[nl], mxv = smx[nl];
        #pragma unroll
        for (int j = 0; j < 4; ++j) {
            const int ml = tx + 16*j;
            float sqd = fmaxf(x2v + sy2[ml] - 2.0f*acc[i][j], 0.0f);
            float r = (mxv - smy[ml]) * INV2PI;
            r -= floorf(r);
            orow[ml] = fastcos_rev(r) * __expf(-0.5f * sqd);
        }
    }
}

extern "C" void kernel_launch(void* const* d_in, const int* in_sizes, int n_in,
                              void* d_out, int out_size, void* d_ws, size_t ws_size,
                              hipStream_t stream)
{
    const float* x   = (const float*)d_in[0];
    const float* y   = (const float*)d_in[1];
    const float* mu  = (const float*)d_in[2];
    const float* ls2 = (const float*)d_in[3];
    float* out = (float*)d_out;

    const int Dd = in_sizes[3];
    const long long BN = in_sizes[0] / Dd;   // B*N
    const long long BM = in_sizes[1] / Dd;   // B*M
    const int B = (int)((BN * BM) / (long long)out_size);
    const int N = (int)(BN / B);
    const int M = (int)(BM / B);

    const size_t need = (size_t)(BN + BM) * D * 2 * 2   // hi+lo bf16
                      + (size_t)(BN + BM) * sizeof(float4);

    if (ws_size >= need && (N % BT_N) == 0 && (M % BT_M) == 0) {
        unsigned short* xh = (unsigned short*)d_ws;
        unsigned short* xl = xh + (size_t)BN * D;
        unsigned short* yh = xl + (size_t)BN * D;
        unsigned short* yl = yh + (size_t)BM * D;
        float4* xst = (float4*)(yl + (size_t)BM * D);
        float4* yst = xst + BN;

        const long long rows8 = (BN + BM) * 8;
        hipLaunchKernelGGL(prep_kernel, dim3((int)((rows8 + 255) / 256)), dim3(256), 0, stream,
                           x, y, mu, ls2, xh, xl, yh, yl, xst, yst, (int)BN, (int)BM);
        hipLaunchKernelGGL(main_kernel, dim3(M / BT_M, N / BT_N, B), dim3(256), 0, stream,
                           xh, xl, yh, yl, xst, yst, out, N, M);
    } else {
        hipLaunchKernelGGL(fallback_kernel, dim3(M / FTILE, N / FTILE, B), dim3(256), 0, stream,
                           x, y, mu, ls2, out, N, M);
    }
}